// Round 3
// baseline (458.701 us; speedup 1.0000x reference)
//
#include <hip/hip_runtime.h>

// 18-wire, 3-layer batched statevector sim. State in-place in d_in[0]/d_in[1] (SoA).
// Wire w <-> bit p = 17-w. Per layer:
//   passB: SQ(bits 17..11) + CNOT(17,16)..(12,11)  [window bits 11..17, 7 bits]
//   passA: SQ(bits 10..0)  + CNOT(11,10)..(1,0)    [window bits 0..10, 11 bits; C(11,10) control n11 external]
// All CNOT chains are classical permutations -> folded into store addresses via
// suffix-XOR cascade: out_k = m_k ^ out_{k+1}. Zero data movement for CNOTs.
// Every wave (64 lanes x 32 regs = 2048 amps) is self-contained: transposes are
// wave-local LDS round trips (stride-36 skew, <=2-way banks). ZERO __syncthreads.

#define LROW 36u           // LDS row stride in floats (144B, 16B-aligned skew)
#define LDSW 2304u         // per-wave LDS floats (64 rows * 36)

static __device__ __forceinline__ float rfl(float x) {
    return __int_as_float(__builtin_amdgcn_readfirstlane(__float_as_int(x)));
}

// SQ gate on register-index bit J: RY(theta_y) then RZ(theta_z) (global phase dropped)
template<int J>
__device__ __forceinline__ void sqg(float* ar, float* ai, float c, float s, float pc, float ps) {
#pragma unroll
    for (int r = 0; r < 32; ++r) {
        if (((r >> J) & 1) == 0) {
            const int r1 = r + (1 << J);
            const float a0r = ar[r], a0i = ai[r], a1r = ar[r1], a1i = ai[r1];
            ar[r] = fmaf(c, a0r, -(s * a1r));
            ai[r] = fmaf(c, a0i, -(s * a1i));
            const float t1r = fmaf(s, a0r, c * a1r);
            const float t1i = fmaf(s, a0i, c * a1i);
            ar[r1] = fmaf(pc, t1r, -(ps * t1i));
            ai[r1] = fmaf(pc, t1i,  (ps * t1r));
        }
    }
}

// ---------------- passB: window bits 11..17 ----------------
// Wave coords: lanes l = [L5..L0] = [m17,m16,m12,m11,m3,m2]; regs idx = [m15..13 | m1,m0].
// Fixed: batch(6) + mid = m10..4 (7 bits) -> 8192 waves = 4096 blocks x 2 waves.
__global__ __launch_bounds__(128) void passB_k(float* __restrict__ re, float* __restrict__ im,
                                               const float* __restrict__ params, int layer)
{
    __shared__ float lds[2 * LDSW];
    const int t   = threadIdx.x;
    const int l   = t & 63;
    const int wib = t >> 6;
    float* Lb = lds + wib * LDSW;
    const int wv  = (blockIdx.x << 1) | wib;
    const int b   = wv >> 7;
    const int mid = wv & 127;
    const int L5 = (l >> 5) & 1, L4 = (l >> 4) & 1, L3 = (l >> 3) & 1, L2 = (l >> 2) & 1;
    const int L1 = (l >> 1) & 1, L0 = l & 1;

    const unsigned base = ((unsigned)b << 18) | ((unsigned)mid << 4);
    const unsigned sel  = (L5 << 17) | (L4 << 16) | (L3 << 12) | (L2 << 11) | (L1 << 3) | (L0 << 2);

    // coefs: k = p-11 (p = bit 11+k), wire = 6-k
    float C[7], S[7], PC[7], PS[7];
    const float* pl = params + layer * 36;
#pragma unroll
    for (int k = 0; k < 7; ++k) {
        const int w = 6 - k;
        float sv, cv;
        __sincosf(0.5f * pl[w], &sv, &cv);  S[k] = rfl(sv);  C[k] = rfl(cv);
        __sincosf(pl[18 + w], &sv, &cv);    PS[k] = rfl(sv); PC[k] = rfl(cv);
    }

    float ar[32], ai[32];
#pragma unroll
    for (int g = 0; g < 8; ++g) {
        const unsigned n = base + sel + ((unsigned)g << 13);
        const float4 vr = *(const float4*)&re[n];
        const float4 vi = *(const float4*)&im[n];
        ar[4*g+0] = vr.x; ar[4*g+1] = vr.y; ar[4*g+2] = vr.z; ar[4*g+3] = vr.w;
        ai[4*g+0] = vi.x; ai[4*g+1] = vi.y; ai[4*g+2] = vi.z; ai[4*g+3] = vi.w;
    }

    // phase 1: idx bits [4:2] = m15,m14,m13 -> SQ(15)=k4, SQ(14)=k3, SQ(13)=k2
    sqg<4>(ar, ai, C[4], S[4], PC[4], PS[4]);
    sqg<3>(ar, ai, C[3], S[3], PC[3], PS[3]);
    sqg<2>(ar, ai, C[2], S[2], PC[2], PS[2]);

    // T1: value (g,c) -> row (g<<3)|(L0<<2)|c, pos = l>>1   (banks <=2-way: free)
    const unsigned tb = (unsigned)L0 * 144u + (unsigned)(l >> 1);
#pragma unroll
    for (int g = 0; g < 8; ++g)
#pragma unroll
        for (int c = 0; c < 4; ++c)
            Lb[tb + g * 288 + c * 36] = ar[4*g+c];
#pragma unroll
    for (int q = 0; q < 8; ++q) {  // row l contiguous: idx2 = [m17,m16,m12,m11,m3]
        const float4 v = *(const float4*)&Lb[(unsigned)l * LROW + (q << 2)];
        ar[4*q+0] = v.x; ar[4*q+1] = v.y; ar[4*q+2] = v.z; ar[4*q+3] = v.w;
    }
#pragma unroll
    for (int g = 0; g < 8; ++g)
#pragma unroll
        for (int c = 0; c < 4; ++c)
            Lb[tb + g * 288 + c * 36] = ai[4*g+c];
#pragma unroll
    for (int q = 0; q < 8; ++q) {
        const float4 v = *(const float4*)&Lb[(unsigned)l * LROW + (q << 2)];
        ai[4*q+0] = v.x; ai[4*q+1] = v.y; ai[4*q+2] = v.z; ai[4*q+3] = v.w;
    }

    // phase 2: idx2 [4]=m17(k6) [3]=m16(k5) [2]=m12(k1) [1]=m11(k0)
    sqg<4>(ar, ai, C[6], S[6], PC[6], PS[6]);
    sqg<3>(ar, ai, C[5], S[5], PC[5], PS[5]);
    sqg<2>(ar, ai, C[1], S[1], PC[1], PS[1]);
    sqg<1>(ar, ai, C[0], S[0], PC[0], PS[0]);

    // T2: write row l contiguous, read scatter back to (g,c) layout
#pragma unroll
    for (int q = 0; q < 8; ++q)
        *(float4*)&Lb[(unsigned)l * LROW + (q << 2)] =
            make_float4(ar[4*q+0], ar[4*q+1], ar[4*q+2], ar[4*q+3]);
#pragma unroll
    for (int g = 0; g < 8; ++g)
#pragma unroll
        for (int c = 0; c < 4; ++c)
            ar[4*g+c] = Lb[tb + g * 288 + c * 36];
#pragma unroll
    for (int q = 0; q < 8; ++q)
        *(float4*)&Lb[(unsigned)l * LROW + (q << 2)] =
            make_float4(ai[4*q+0], ai[4*q+1], ai[4*q+2], ai[4*q+3]);
#pragma unroll
    for (int g = 0; g < 8; ++g)
#pragma unroll
        for (int c = 0; c < 4; ++c)
            ai[4*g+c] = Lb[tb + g * 288 + c * 36];

    // store: chain C(17,16)..C(12,11) folded: h = [m17..m11], out = suffix-xor(h)
#pragma unroll
    for (int g = 0; g < 8; ++g) {
        int h = (L5 << 6) | (L4 << 5) | (g << 2) | (L3 << 1) | L2;
        int x = h ^ (h >> 1); x ^= x >> 2; x ^= x >> 4;
        const unsigned n = base + ((unsigned)x << 11) + (L1 << 3) + (L0 << 2);
        *(float4*)&re[n] = make_float4(ar[4*g+0], ar[4*g+1], ar[4*g+2], ar[4*g+3]);
        *(float4*)&im[n] = make_float4(ai[4*g+0], ai[4*g+1], ai[4*g+2], ai[4*g+3]);
    }
}

// ---------------- passA: window bits 0..10 (one wave) ----------------
// Wave coords: lanes l = m7..2; regs idx = [m10..8 | m1,m0]. Fixed: batch + hi7 = n17..11.
template<bool FINAL>
__global__ __launch_bounds__(128) void passA_k(float* __restrict__ re, float* __restrict__ im,
                                               const float* __restrict__ params, int layer,
                                               const float* __restrict__ hw,
                                               const float* __restrict__ hb,
                                               float* __restrict__ out)
{
    __shared__ float lds[2 * LDSW];
    const int t   = threadIdx.x;
    const int l   = t & 63;
    const int wib = t >> 6;
    float* Lb = lds + wib * LDSW;
    const int wv  = (blockIdx.x << 1) | wib;
    const int b   = wv >> 7;
    const int hi7 = wv & 127;
    const int n11 = hi7 & 1;
    const unsigned base = ((unsigned)b << 18) | ((unsigned)hi7 << 11);

    // coefs: k = bit p (0..10), wire = 17-p
    float C[11], S[11], PC[11], PS[11];
    const float* pl = params + layer * 36;
#pragma unroll
    for (int k = 0; k < 11; ++k) {
        const int w = 17 - k;
        float sv, cv;
        __sincosf(0.5f * pl[w], &sv, &cv);  S[k] = rfl(sv);  C[k] = rfl(cv);
        __sincosf(pl[18 + w], &sv, &cv);    PS[k] = rfl(sv); PC[k] = rfl(cv);
    }

    float ar[32], ai[32];
#pragma unroll
    for (int g = 0; g < 8; ++g) {   // fully coalesced: 1KB contiguous per instr
        const unsigned n = base + ((unsigned)g << 8) + ((unsigned)l << 2);
        const float4 vr = *(const float4*)&re[n];
        const float4 vi = *(const float4*)&im[n];
        ar[4*g+0] = vr.x; ar[4*g+1] = vr.y; ar[4*g+2] = vr.z; ar[4*g+3] = vr.w;
        ai[4*g+0] = vi.x; ai[4*g+1] = vi.y; ai[4*g+2] = vi.z; ai[4*g+3] = vi.w;
    }

    // phase 1 reg-gates: SQ(10),SQ(9),SQ(8) on idx[4:2]; SQ(1),SQ(0) on idx[1:0]
    sqg<4>(ar, ai, C[10], S[10], PC[10], PS[10]);
    sqg<3>(ar, ai, C[9],  S[9],  PC[9],  PS[9]);
    sqg<2>(ar, ai, C[8],  S[8],  PC[8],  PS[8]);
    sqg<1>(ar, ai, C[1],  S[1],  PC[1],  PS[1]);
    sqg<0>(ar, ai, C[0],  S[0],  PC[0],  PS[0]);

    // lane-gate SQ(7): m7 = lane bit 5, partner = shfl_xor 32
    {
        const int side   = (l >> 5) & 1;
        const float c7   = C[7];
        const float bco  = side ? S[7] : -S[7];
        const float qc   = side ? PC[7] : 1.f;
        const float qs   = side ? PS[7] : 0.f;
#pragma unroll
        for (int r = 0; r < 32; ++r) {
            const float pr = __shfl_xor(ar[r], 32);
            const float pi = __shfl_xor(ai[r], 32);
            const float tr = fmaf(c7, ar[r], bco * pr);
            const float ti = fmaf(c7, ai[r], bco * pi);
            ar[r] = fmaf(qc, tr, -(qs * ti));
            ai[r] = fmaf(qc, ti,  (qs * tr));
        }
    }

    // T1: value (g,c) -> row (g<<3)|(m7<<2)|c, pos = l&31  (banks <=2-way: free)
    const unsigned tb = (unsigned)((l >> 5) & 1) * 144u + (unsigned)(l & 31);
#pragma unroll
    for (int g = 0; g < 8; ++g)
#pragma unroll
        for (int c = 0; c < 4; ++c)
            Lb[tb + g * 288 + c * 36] = ar[4*g+c];
#pragma unroll
    for (int q = 0; q < 8; ++q) {   // row l contiguous: idx2 = m6..2
        const float4 v = *(const float4*)&Lb[(unsigned)l * LROW + (q << 2)];
        ar[4*q+0] = v.x; ar[4*q+1] = v.y; ar[4*q+2] = v.z; ar[4*q+3] = v.w;
    }
#pragma unroll
    for (int g = 0; g < 8; ++g)
#pragma unroll
        for (int c = 0; c < 4; ++c)
            Lb[tb + g * 288 + c * 36] = ai[4*g+c];
#pragma unroll
    for (int q = 0; q < 8; ++q) {
        const float4 v = *(const float4*)&Lb[(unsigned)l * LROW + (q << 2)];
        ai[4*q+0] = v.x; ai[4*q+1] = v.y; ai[4*q+2] = v.z; ai[4*q+3] = v.w;
    }

    // phase 2: idx2 bit j = m(j+2): SQ(6..2)
    sqg<4>(ar, ai, C[6], S[6], PC[6], PS[6]);
    sqg<3>(ar, ai, C[5], S[5], PC[5], PS[5]);
    sqg<2>(ar, ai, C[4], S[4], PC[4], PS[4]);
    sqg<1>(ar, ai, C[3], S[3], PC[3], PS[3]);
    sqg<0>(ar, ai, C[2], S[2], PC[2], PS[2]);

    // T2: back to (g,c) layout
#pragma unroll
    for (int q = 0; q < 8; ++q)
        *(float4*)&Lb[(unsigned)l * LROW + (q << 2)] =
            make_float4(ar[4*q+0], ar[4*q+1], ar[4*q+2], ar[4*q+3]);
#pragma unroll
    for (int g = 0; g < 8; ++g)
#pragma unroll
        for (int c = 0; c < 4; ++c)
            ar[4*g+c] = Lb[tb + g * 288 + c * 36];
#pragma unroll
    for (int q = 0; q < 8; ++q)
        *(float4*)&Lb[(unsigned)l * LROW + (q << 2)] =
            make_float4(ai[4*q+0], ai[4*q+1], ai[4*q+2], ai[4*q+3]);
#pragma unroll
    for (int g = 0; g < 8; ++g)
#pragma unroll
        for (int c = 0; c < 4; ++c)
            ai[4*g+c] = Lb[tb + g * 288 + c * 36];

    const int msk = n11 ? 0x1FF : 0;

    if (!FINAL) {
        // chain C(11,10)..C(1,0) folded into store address: out = sxor(m10..2) ^ n11-mask
#pragma unroll
        for (int g = 0; g < 8; ++g) {
            int h = (g << 6) | l;
            int x = h ^ (h >> 1); x ^= x >> 2; x ^= x >> 4; x ^= x >> 8;
            x ^= msk;
            const int y = x & 1;  // = out2: selects in-quad permutation
            const float r0 = ar[4*g+0], r1 = ar[4*g+1], r2 = ar[4*g+2], r3 = ar[4*g+3];
            const float i0 = ai[4*g+0], i1 = ai[4*g+1], i2 = ai[4*g+2], i3 = ai[4*g+3];
            float4 sr, si;
            sr.x = y ? r2 : r0;  sr.y = y ? r3 : r1;  sr.z = y ? r1 : r3;  sr.w = y ? r0 : r2;
            si.x = y ? i2 : i0;  si.y = y ? i3 : i1;  si.z = y ? i1 : i3;  si.w = y ? i0 : i2;
            const unsigned n = base + ((unsigned)x << 2);
            *(float4*)&re[n] = sr;
            *(float4*)&im[n] = si;
        }
    } else {
        // expval + head. Probabilities are permutation-invariant; signs use true (cascaded) bits.
        float Ghi = 0.f;
#pragma unroll
        for (int j = 0; j < 7; ++j) {   // bits 11..17 <-> wires 6..0
            const float wv_ = hw[6 - j];
            Ghi += ((hi7 >> j) & 1) ? -wv_ : wv_;
        }
        float acc = 0.f;
#pragma unroll
        for (int g = 0; g < 8; ++g) {
            int h = (g << 6) | l;
            int x = h ^ (h >> 1); x ^= x >> 2; x ^= x >> 4; x ^= x >> 8;
            x ^= msk;
            const float q0 = fmaf(ar[4*g+0], ar[4*g+0], ai[4*g+0] * ai[4*g+0]);
            const float q1 = fmaf(ar[4*g+1], ar[4*g+1], ai[4*g+1] * ai[4*g+1]);
            const float q2 = fmaf(ar[4*g+2], ar[4*g+2], ai[4*g+2] * ai[4*g+2]);
            const float q3 = fmaf(ar[4*g+3], ar[4*g+3], ai[4*g+3] * ai[4*g+3]);
            const float psum = (q0 + q1) + (q2 + q3);
            const float d1   = (q0 + q1) - (q2 + q3);   // sign by out1 (wire 16), pre (-1)^y
            const float d0   = (q0 - q1) - (q2 - q3);   // sign by out0 (wire 17), pre (-1)^y
            float Gm = 0.f;
#pragma unroll
            for (int j = 0; j < 9; ++j) {   // x bit j = out_{j+2} <-> wire 15-j
                const float wv_ = hw[15 - j];
                Gm += ((x >> j) & 1) ? -wv_ : wv_;
            }
            const float ys = (x & 1) ? -1.f : 1.f;
            acc += psum * (Ghi + Gm) + ys * fmaf(d1, hw[16], d0 * hw[17]);
        }
        if (hi7 == 0 && l == 0) acc += hb[0];
#pragma unroll
        for (int off = 32; off > 0; off >>= 1) acc += __shfl_xor(acc, off);
        if (l == 0) atomicAdd(&out[b], acc);
    }
}

extern "C" void kernel_launch(void* const* d_in, const int* in_sizes, int n_in,
                              void* d_out, int out_size, void* d_ws, size_t ws_size,
                              hipStream_t stream)
{
    float* re           = (float*)d_in[0];
    float* im           = (float*)d_in[1];
    const float* params = (const float*)d_in[2];
    const float* hw     = (const float*)d_in[3];
    const float* hb     = (const float*)d_in[4];
    float* out          = (float*)d_out;
    (void)in_sizes; (void)n_in; (void)d_ws; (void)ws_size;

    hipMemsetAsync(out, 0, (size_t)out_size * sizeof(float), stream);

    const dim3 grid(4096), blk(128);
    for (int l = 0; l < 3; ++l) {
        passB_k<<<grid, blk, 0, stream>>>(re, im, params, l);
        if (l < 2) passA_k<false><<<grid, blk, 0, stream>>>(re, im, params, l, nullptr, nullptr, nullptr);
        else       passA_k<true ><<<grid, blk, 0, stream>>>(re, im, params, l, hw, hb, out);
    }
}

// Round 4
// 396.784 us; speedup vs baseline: 1.1560x; 1.1560x over previous
//
#include <hip/hip_runtime.h>

// 18-wire, 3-layer batched statevector sim. Intermediate state = PACKED bf16
// (re | im<<16) in one uint32 per amplitude, ping-ponged between d_in[0] and
// d_in[1] (each exactly 64*2^18*4 B = one packed state). Compute is fp32.
//
// Wire w <-> bit p = 17-w. Per layer:
//   passB: SQ(bits 17..11) + CNOT(17,16)..(12,11)  [hi window]
//   passA: SQ(bits 10..0)  + CNOT(11,10)..(1,0)    [lo window; control n11 external]
// CNOT chains are classical XOR-permutations folded into store addressing
// (suffix-xor cascade). Pass B_1 reads the fp32 inputs and stores packed bf16
// UNPERMUTED at its own read addresses (byte-exact in-place over d_in[0]);
// its hi-bit permutation is deferred to A_1's load addressing as a free
// block relabel hi7_phys = L ^ (L>>1). All other passes ping-pong race-free.
// Zero __syncthreads anywhere; transposes are wave-local LDS round trips.

#define LROW 36u           // LDS row stride in floats (144B, 16B-aligned skew)
#define LDSW 2304u         // per-wave LDS floats (64 rows * 36)

static __device__ __forceinline__ float rfl(float x) {
    return __int_as_float(__builtin_amdgcn_readfirstlane(__float_as_int(x)));
}

static __device__ __forceinline__ void unpack2(unsigned u, float& re, float& im) {
    re = __uint_as_float(u << 16);
    im = __uint_as_float(u & 0xFFFF0000u);
}
static __device__ __forceinline__ unsigned packbf(float a, float b) {  // RNE
    unsigned ua = __float_as_uint(a); ua += 0x7FFFu + ((ua >> 16) & 1u);
    unsigned ub = __float_as_uint(b); ub += 0x7FFFu + ((ub >> 16) & 1u);
    return (ua >> 16) | (ub & 0xFFFF0000u);
}

// one RY+RZ on an amplitude pair (RZ global phase dropped)
static __device__ __forceinline__ void sq_pair(float& a0r, float& a0i, float& a1r, float& a1i,
                                               float c, float s, float pc, float ps) {
    const float t0r = fmaf(c, a0r, -(s * a1r));
    const float t0i = fmaf(c, a0i, -(s * a1i));
    const float t1r = fmaf(s, a0r,  c * a1r);
    const float t1i = fmaf(s, a0i,  c * a1i);
    a0r = t0r; a0i = t0i;
    a1r = fmaf(pc, t1r, -(ps * t1i));
    a1i = fmaf(pc, t1i,  (ps * t1r));
}

template<int J>
__device__ __forceinline__ void sqg(float* ar, float* ai, float c, float s, float pc, float ps) {
#pragma unroll
    for (int r = 0; r < 32; ++r) {
        if (((r >> J) & 1) == 0) {
            const int r1 = r + (1 << J);
            sq_pair(ar[r], ai[r], ar[r1], ai[r1], c, s, pc, ps);
        }
    }
}

// ---------------- passB common gate/transpose body ----------------
// Wave coords: lanes l = [L5..L0] = [m17,m16,m12,m11,m3,m2]; regs idx = [m15..13 | m1,m0].
// Fixed: batch(6) + mid = m10..4 (7 bits).
struct BCoef { float C[7], S[7], PC[7], PS[7]; };

static __device__ __forceinline__ void passB_body(float* ar, float* ai, float* Lb,
                                                  const BCoef& k, int l) {
    const int L0 = l & 1;
    // phase 1: idx bits [4:2] = m15,m14,m13 -> coeff idx 4,3,2
    sqg<4>(ar, ai, k.C[4], k.S[4], k.PC[4], k.PS[4]);
    sqg<3>(ar, ai, k.C[3], k.S[3], k.PC[3], k.PS[3]);
    sqg<2>(ar, ai, k.C[2], k.S[2], k.PC[2], k.PS[2]);

    // T1: value (g,c) -> row (g<<3)|(L0<<2)|c, pos = l>>1   (banks <=2-way: free)
    const unsigned tb = (unsigned)L0 * 144u + (unsigned)(l >> 1);
#pragma unroll
    for (int g = 0; g < 8; ++g)
#pragma unroll
        for (int c = 0; c < 4; ++c)
            Lb[tb + g * 288 + c * 36] = ar[4*g+c];
#pragma unroll
    for (int q = 0; q < 8; ++q) {  // row l contiguous: idx2 = [m17,m16,m12,m11,m3]
        const float4 v = *(const float4*)&Lb[(unsigned)l * LROW + (q << 2)];
        ar[4*q+0] = v.x; ar[4*q+1] = v.y; ar[4*q+2] = v.z; ar[4*q+3] = v.w;
    }
#pragma unroll
    for (int g = 0; g < 8; ++g)
#pragma unroll
        for (int c = 0; c < 4; ++c)
            Lb[tb + g * 288 + c * 36] = ai[4*g+c];
#pragma unroll
    for (int q = 0; q < 8; ++q) {
        const float4 v = *(const float4*)&Lb[(unsigned)l * LROW + (q << 2)];
        ai[4*q+0] = v.x; ai[4*q+1] = v.y; ai[4*q+2] = v.z; ai[4*q+3] = v.w;
    }

    // phase 2: idx2 [4]=m17(k6) [3]=m16(k5) [2]=m12(k1) [1]=m11(k0)
    sqg<4>(ar, ai, k.C[6], k.S[6], k.PC[6], k.PS[6]);
    sqg<3>(ar, ai, k.C[5], k.S[5], k.PC[5], k.PS[5]);
    sqg<2>(ar, ai, k.C[1], k.S[1], k.PC[1], k.PS[1]);
    sqg<1>(ar, ai, k.C[0], k.S[0], k.PC[0], k.PS[0]);

    // T2: write row l contiguous, read scatter back to (g,c) layout
#pragma unroll
    for (int q = 0; q < 8; ++q)
        *(float4*)&Lb[(unsigned)l * LROW + (q << 2)] =
            make_float4(ar[4*q+0], ar[4*q+1], ar[4*q+2], ar[4*q+3]);
#pragma unroll
    for (int g = 0; g < 8; ++g)
#pragma unroll
        for (int c = 0; c < 4; ++c)
            ar[4*g+c] = Lb[tb + g * 288 + c * 36];
#pragma unroll
    for (int q = 0; q < 8; ++q)
        *(float4*)&Lb[(unsigned)l * LROW + (q << 2)] =
            make_float4(ai[4*q+0], ai[4*q+1], ai[4*q+2], ai[4*q+3]);
#pragma unroll
    for (int g = 0; g < 8; ++g)
#pragma unroll
        for (int c = 0; c < 4; ++c)
            ai[4*g+c] = Lb[tb + g * 288 + c * 36];
}

static __device__ __forceinline__ void passB_coefs(BCoef& k, const float* pl) {
#pragma unroll
    for (int j = 0; j < 7; ++j) {
        const int w = 6 - j;
        float sv, cv;
        __sincosf(0.5f * pl[w], &sv, &cv);  k.S[j] = rfl(sv);  k.C[j] = rfl(cv);
        __sincosf(pl[18 + w], &sv, &cv);    k.PS[j] = rfl(sv); k.PC[j] = rfl(cv);
    }
}

// passB_1: fp32 planes -> packed bf16 in u (== (unsigned*)re plane), UNPERMUTED store.
// NOTE: re and u alias by design — no __restrict__ on them.
__global__ __launch_bounds__(128) void passB1_k(const float* re, const float* im,
                                                unsigned* u, const float* __restrict__ params)
{
    __shared__ float lds[2 * LDSW];
    const int t   = threadIdx.x;
    const int l   = t & 63;
    const int wib = t >> 6;
    float* Lb = lds + wib * LDSW;
    const int wv  = ((int)blockIdx.x << 1) | wib;
    const int b   = wv >> 7;
    const int mid = wv & 127;
    const int L5 = (l >> 5) & 1, L4 = (l >> 4) & 1, L3 = (l >> 3) & 1, L2 = (l >> 2) & 1;
    const int L1 = (l >> 1) & 1, L0 = l & 1;

    const unsigned base = ((unsigned)b << 18) | ((unsigned)mid << 4);
    const unsigned sel  = (L5 << 17) | (L4 << 16) | (L3 << 12) | (L2 << 11) | (L1 << 3) | (L0 << 2);

    float ar[32], ai[32];
#pragma unroll
    for (int g = 0; g < 8; ++g) {
        const unsigned n = base + sel + ((unsigned)g << 13);
        const float4 vr = *(const float4*)&re[n];
        const float4 vi = *(const float4*)&im[n];
        ar[4*g+0] = vr.x; ar[4*g+1] = vr.y; ar[4*g+2] = vr.z; ar[4*g+3] = vr.w;
        ai[4*g+0] = vi.x; ai[4*g+1] = vi.y; ai[4*g+2] = vi.z; ai[4*g+3] = vi.w;
    }

    BCoef k; passB_coefs(k, params);          // layer 0
    passB_body(ar, ai, Lb, k, l);

    // UNPERMUTED store (perm deferred to A_1's block relabel): in-place safe.
#pragma unroll
    for (int g = 0; g < 8; ++g) {
        const int h = (L5 << 6) | (L4 << 5) | (g << 2) | (L3 << 1) | L2;
        const unsigned n = base + ((unsigned)h << 11) + (L1 << 3) + (L0 << 2);
        uint4 pv;
        pv.x = packbf(ar[4*g+0], ai[4*g+0]);
        pv.y = packbf(ar[4*g+1], ai[4*g+1]);
        pv.z = packbf(ar[4*g+2], ai[4*g+2]);
        pv.w = packbf(ar[4*g+3], ai[4*g+3]);
        *(uint4*)&u[n] = pv;
    }
}

// passB layers 1,2: packed bf16 src -> packed bf16 dst (ping-pong), perm materialized.
__global__ __launch_bounds__(128) void passBk_k(const unsigned* __restrict__ src,
                                                unsigned* __restrict__ dst,
                                                const float* __restrict__ params, int layer)
{
    __shared__ float lds[2 * LDSW];
    const int t   = threadIdx.x;
    const int l   = t & 63;
    const int wib = t >> 6;
    float* Lb = lds + wib * LDSW;
    const int wv  = ((int)blockIdx.x << 1) | wib;
    const int b   = wv >> 7;
    const int mid = wv & 127;
    const int L5 = (l >> 5) & 1, L4 = (l >> 4) & 1, L3 = (l >> 3) & 1, L2 = (l >> 2) & 1;
    const int L1 = (l >> 1) & 1, L0 = l & 1;

    const unsigned base = ((unsigned)b << 18) | ((unsigned)mid << 4);
    const unsigned sel  = (L5 << 17) | (L4 << 16) | (L3 << 12) | (L2 << 11) | (L1 << 3) | (L0 << 2);

    float ar[32], ai[32];
#pragma unroll
    for (int g = 0; g < 8; ++g) {
        const unsigned n = base + sel + ((unsigned)g << 13);
        const uint4 pv = *(const uint4*)&src[n];
        unpack2(pv.x, ar[4*g+0], ai[4*g+0]);
        unpack2(pv.y, ar[4*g+1], ai[4*g+1]);
        unpack2(pv.z, ar[4*g+2], ai[4*g+2]);
        unpack2(pv.w, ar[4*g+3], ai[4*g+3]);
    }

    BCoef k; passB_coefs(k, params + layer * 36);
    passB_body(ar, ai, Lb, k, l);

    // permuted store: h = [m17..m11], x = suffix-xor(h)
#pragma unroll
    for (int g = 0; g < 8; ++g) {
        int h = (L5 << 6) | (L4 << 5) | (g << 2) | (L3 << 1) | L2;
        int x = h ^ (h >> 1); x ^= x >> 2; x ^= x >> 4;
        const unsigned n = base + ((unsigned)x << 11) + (L1 << 3) + (L0 << 2);
        uint4 pv;
        pv.x = packbf(ar[4*g+0], ai[4*g+0]);
        pv.y = packbf(ar[4*g+1], ai[4*g+1]);
        pv.z = packbf(ar[4*g+2], ai[4*g+2]);
        pv.w = packbf(ar[4*g+3], ai[4*g+3]);
        *(uint4*)&dst[n] = pv;
    }
}

// ---------------- passA: window bits 0..10 (one wave) ----------------
// Lanes l = m7..2; regs idx = [m10..8 | m1,m0]. Fixed: batch + hi7 = n17..11.
// FIRST: loads use physical block hi7p = L ^ (L>>1)  (B_1's deferred perm).
template<bool FIRST, bool FINAL>
__global__ __launch_bounds__(128) void passA_k(const unsigned* __restrict__ src,
                                               unsigned* __restrict__ dst,
                                               const float* __restrict__ params, int layer,
                                               const float* __restrict__ hw,
                                               const float* __restrict__ hb,
                                               float* __restrict__ out)
{
    __shared__ float lds[2 * LDSW];
    const int t   = threadIdx.x;
    const int l   = t & 63;
    const int wib = t >> 6;
    float* Lb = lds + wib * LDSW;
    const int wv  = ((int)blockIdx.x << 1) | wib;
    const int b   = wv >> 7;
    const int L   = wv & 127;                       // logical hi7
    const int hip = FIRST ? (L ^ (L >> 1)) : L;     // physical hi7 for loads
    const int n11 = L & 1;
    const unsigned baseL = ((unsigned)b << 18) | ((unsigned)hip << 11);
    const unsigned baseS = ((unsigned)b << 18) | ((unsigned)L << 11);

    // issue all loads first (addresses cheap), coefs + quad gates hide the drain
    uint4 U[8];
#pragma unroll
    for (int g = 0; g < 8; ++g)
        U[g] = *(const uint4*)&src[baseL + ((unsigned)g << 8) + ((unsigned)l << 2)];

    // coefs: idx p (0..10) <-> wire 17-p
    float C[11], S[11], PC[11], PS[11];
    const float* pl = params + layer * 36;
#pragma unroll
    for (int p = 0; p < 11; ++p) {
        const int w = 17 - p;
        float sv, cv;
        __sincosf(0.5f * pl[w], &sv, &cv);  S[p] = rfl(sv);  C[p] = rfl(cv);
        __sincosf(pl[18 + w], &sv, &cv);    PS[p] = rfl(sv); PC[p] = rfl(cv);
    }

    float ar[32], ai[32];
    // per-quad: unpack + quad-local gates SQ(1),SQ(0) as each load lands
#pragma unroll
    for (int g = 0; g < 8; ++g) {
        unpack2(U[g].x, ar[4*g+0], ai[4*g+0]);
        unpack2(U[g].y, ar[4*g+1], ai[4*g+1]);
        unpack2(U[g].z, ar[4*g+2], ai[4*g+2]);
        unpack2(U[g].w, ar[4*g+3], ai[4*g+3]);
        sq_pair(ar[4*g+0], ai[4*g+0], ar[4*g+2], ai[4*g+2], C[1], S[1], PC[1], PS[1]); // m1
        sq_pair(ar[4*g+1], ai[4*g+1], ar[4*g+3], ai[4*g+3], C[1], S[1], PC[1], PS[1]);
        sq_pair(ar[4*g+0], ai[4*g+0], ar[4*g+1], ai[4*g+1], C[0], S[0], PC[0], PS[0]); // m0
        sq_pair(ar[4*g+2], ai[4*g+2], ar[4*g+3], ai[4*g+3], C[0], S[0], PC[0], PS[0]);
    }

    // cross-quad phase 1: SQ(10),SQ(9),SQ(8) on idx bits 4..2
    sqg<4>(ar, ai, C[10], S[10], PC[10], PS[10]);
    sqg<3>(ar, ai, C[9],  S[9],  PC[9],  PS[9]);
    sqg<2>(ar, ai, C[8],  S[8],  PC[8],  PS[8]);

    // lane-gate SQ(7): m7 = lane bit 5, partner = shfl_xor 32
    {
        const int side   = (l >> 5) & 1;
        const float c7   = C[7];
        const float bco  = side ? S[7] : -S[7];
        const float qc   = side ? PC[7] : 1.f;
        const float qs   = side ? PS[7] : 0.f;
#pragma unroll
        for (int r = 0; r < 32; ++r) {
            const float pr = __shfl_xor(ar[r], 32);
            const float pi = __shfl_xor(ai[r], 32);
            const float tr = fmaf(c7, ar[r], bco * pr);
            const float ti = fmaf(c7, ai[r], bco * pi);
            ar[r] = fmaf(qc, tr, -(qs * ti));
            ai[r] = fmaf(qc, ti,  (qs * tr));
        }
    }

    // T1: value (g,c) -> row (g<<3)|(m7<<2)|c, pos = l&31  (banks <=2-way: free)
    const unsigned tb = (unsigned)((l >> 5) & 1) * 144u + (unsigned)(l & 31);
#pragma unroll
    for (int g = 0; g < 8; ++g)
#pragma unroll
        for (int c = 0; c < 4; ++c)
            Lb[tb + g * 288 + c * 36] = ar[4*g+c];
#pragma unroll
    for (int q = 0; q < 8; ++q) {   // row l contiguous: idx2 = m6..2
        const float4 v = *(const float4*)&Lb[(unsigned)l * LROW + (q << 2)];
        ar[4*q+0] = v.x; ar[4*q+1] = v.y; ar[4*q+2] = v.z; ar[4*q+3] = v.w;
    }
#pragma unroll
    for (int g = 0; g < 8; ++g)
#pragma unroll
        for (int c = 0; c < 4; ++c)
            Lb[tb + g * 288 + c * 36] = ai[4*g+c];
#pragma unroll
    for (int q = 0; q < 8; ++q) {
        const float4 v = *(const float4*)&Lb[(unsigned)l * LROW + (q << 2)];
        ai[4*q+0] = v.x; ai[4*q+1] = v.y; ai[4*q+2] = v.z; ai[4*q+3] = v.w;
    }

    // phase 2: idx2 bit j = m(j+2): SQ(6..2)
    sqg<4>(ar, ai, C[6], S[6], PC[6], PS[6]);
    sqg<3>(ar, ai, C[5], S[5], PC[5], PS[5]);
    sqg<2>(ar, ai, C[4], S[4], PC[4], PS[4]);
    sqg<1>(ar, ai, C[3], S[3], PC[3], PS[3]);
    sqg<0>(ar, ai, C[2], S[2], PC[2], PS[2]);

    // T2: back to (g,c) layout
#pragma unroll
    for (int q = 0; q < 8; ++q)
        *(float4*)&Lb[(unsigned)l * LROW + (q << 2)] =
            make_float4(ar[4*q+0], ar[4*q+1], ar[4*q+2], ar[4*q+3]);
#pragma unroll
    for (int g = 0; g < 8; ++g)
#pragma unroll
        for (int c = 0; c < 4; ++c)
            ar[4*g+c] = Lb[tb + g * 288 + c * 36];
#pragma unroll
    for (int q = 0; q < 8; ++q)
        *(float4*)&Lb[(unsigned)l * LROW + (q << 2)] =
            make_float4(ai[4*q+0], ai[4*q+1], ai[4*q+2], ai[4*q+3]);
#pragma unroll
    for (int g = 0; g < 8; ++g)
#pragma unroll
        for (int c = 0; c < 4; ++c)
            ai[4*g+c] = Lb[tb + g * 288 + c * 36];

    const int msk = n11 ? 0x1FF : 0;

    if (!FINAL) {
        // chain C(11,10)..(1,0) folded into store address: out = sxor(m10..2) ^ msk
#pragma unroll
        for (int g = 0; g < 8; ++g) {
            int h = (g << 6) | l;
            int x = h ^ (h >> 1); x ^= x >> 2; x ^= x >> 4; x ^= x >> 8;
            x ^= msk;
            const int y = x & 1;  // in-quad permutation select
            const float r0 = ar[4*g+0], r1 = ar[4*g+1], r2 = ar[4*g+2], r3 = ar[4*g+3];
            const float i0 = ai[4*g+0], i1 = ai[4*g+1], i2 = ai[4*g+2], i3 = ai[4*g+3];
            uint4 pv;
            pv.x = y ? packbf(r2, i2) : packbf(r0, i0);
            pv.y = y ? packbf(r3, i3) : packbf(r1, i1);
            pv.z = y ? packbf(r1, i1) : packbf(r3, i3);
            pv.w = y ? packbf(r0, i0) : packbf(r2, i2);
            *(uint4*)&dst[baseS + ((unsigned)x << 2)] = pv;
        }
    } else {
        // expval + head (probabilities permutation-invariant; signs use cascaded bits)
        float Ghi = 0.f;
#pragma unroll
        for (int j = 0; j < 7; ++j) {   // bits 11..17 <-> wires 6..0
            const float wv_ = hw[6 - j];
            Ghi += ((L >> j) & 1) ? -wv_ : wv_;
        }
        float acc = 0.f;
#pragma unroll
        for (int g = 0; g < 8; ++g) {
            int h = (g << 6) | l;
            int x = h ^ (h >> 1); x ^= x >> 2; x ^= x >> 4; x ^= x >> 8;
            x ^= msk;
            const float q0 = fmaf(ar[4*g+0], ar[4*g+0], ai[4*g+0] * ai[4*g+0]);
            const float q1 = fmaf(ar[4*g+1], ar[4*g+1], ai[4*g+1] * ai[4*g+1]);
            const float q2 = fmaf(ar[4*g+2], ar[4*g+2], ai[4*g+2] * ai[4*g+2]);
            const float q3 = fmaf(ar[4*g+3], ar[4*g+3], ai[4*g+3] * ai[4*g+3]);
            const float psum = (q0 + q1) + (q2 + q3);
            const float d1   = (q0 + q1) - (q2 + q3);
            const float d0   = (q0 - q1) - (q2 - q3);
            float Gm = 0.f;
#pragma unroll
            for (int j = 0; j < 9; ++j) {   // x bit j = out_{j+2} <-> wire 15-j
                const float wv_ = hw[15 - j];
                Gm += ((x >> j) & 1) ? -wv_ : wv_;
            }
            const float ys = (x & 1) ? -1.f : 1.f;
            acc += psum * (Ghi + Gm) + ys * fmaf(d1, hw[16], d0 * hw[17]);
        }
        if (L == 0 && l == 0) acc += hb[0];
#pragma unroll
        for (int off = 32; off > 0; off >>= 1) acc += __shfl_xor(acc, off);
        if (l == 0) atomicAdd(&out[b], acc);
    }
}

extern "C" void kernel_launch(void* const* d_in, const int* in_sizes, int n_in,
                              void* d_out, int out_size, void* d_ws, size_t ws_size,
                              hipStream_t stream)
{
    const float* re0    = (const float*)d_in[0];
    const float* im0    = (const float*)d_in[1];
    unsigned* u0        = (unsigned*)d_in[0];   // packed bf16 state, ping
    unsigned* u1        = (unsigned*)d_in[1];   // packed bf16 state, pong
    const float* params = (const float*)d_in[2];
    const float* hw     = (const float*)d_in[3];
    const float* hb     = (const float*)d_in[4];
    float* out          = (float*)d_out;
    (void)in_sizes; (void)n_in; (void)d_ws; (void)ws_size;

    hipMemsetAsync(out, 0, (size_t)out_size * sizeof(float), stream);

    const dim3 grid(4096), blk(128);
    passB1_k             <<<grid, blk, 0, stream>>>(re0, im0, u0, params);
    passA_k<true,  false><<<grid, blk, 0, stream>>>(u0, u1, params, 0, nullptr, nullptr, nullptr);
    passBk_k             <<<grid, blk, 0, stream>>>(u1, u0, params, 1);
    passA_k<false, false><<<grid, blk, 0, stream>>>(u0, u1, params, 1, nullptr, nullptr, nullptr);
    passBk_k             <<<grid, blk, 0, stream>>>(u1, u0, params, 2);
    passA_k<false, true ><<<grid, blk, 0, stream>>>(u0, nullptr, params, 2, hw, hb, out);
}